// Round 4
// baseline (166.444 us; speedup 1.0000x reference)
//
#include <hip/hip_runtime.h>

namespace {
constexpr int N   = 64;
constexpr int D   = 32;
constexpr int PD  = 36;  // padded ind row (dwords): stride-36 measured conflict-free (r1/r2)
constexpr int SHP = 68;  // sh row pad: bank = (4*i + lane) % 32 -> <=2-way (free)
constexpr float LOG2E = 1.4426950408889634f;
constexpr float LN2   = 0.6931471805599453f;

#if __has_builtin(__builtin_amdgcn_exp2f)
__device__ __forceinline__ float fexp2(float x) { return __builtin_amdgcn_exp2f(x); }
#else
__device__ __forceinline__ float fexp2(float x) { return exp2f(x); }
#endif
#if __has_builtin(__builtin_amdgcn_rcpf)
__device__ __forceinline__ float frcp(float x) { return __builtin_amdgcn_rcpf(x); }
#else
__device__ __forceinline__ float frcp(float x) { return 1.0f / x; }
#endif

// Grid 1024 = 2 blocks per b (32 i-rows each), block 512 (8 waves).
// LDS 37.1 KB -> 4 blocks/CU; VGPR capped <=64 -> 8 waves/SIMD; 32 waves/CU.
// Wave owns 4 rows; gate for those rows computed into registers (no gate LDS:
// r3's gate_lds writes were the 196K bank-conflict source).
// Single-exp identity (exact, verified r3):
//   elup1(a)*elup1(b) = exp2(min(aL,0)+min(bL,0)) * (1+max(aL,0)*ln2) * (1+max(bL,0)*ln2)
// with aL,bL pre-scaled by log2e.
__global__ __launch_bounds__(512, 8) void fused(
        const float* __restrict__ feature,
        const float* __restrict__ ind,
        float* __restrict__ out) {
    __shared__ float ind_lds[3][N][PD];   // 27648 B
    __shared__ float s_lds[3][N];         //   768 B
    __shared__ float sh_lds[32][SHP];     //  8704 B   total 37120 B

    const int t      = threadIdx.x;
    const int lane   = t & 63;
    const int wave   = t >> 6;
    const int blk    = blockIdx.x;
    const int b      = blk >> 1;
    const int i_base = (blk & 1) << 5;

    // ---- stage indicator: 1536 float4, 3 per thread, coalesced (pattern
    //      measured conflict-free in r1/r2) ----
    {
        const float4* src = reinterpret_cast<const float4*>(ind);
#pragma unroll
        for (int idx = t; idx < 3 * N * D / 4; idx += 512) {
            int a = idx >> 9;
            int r = idx & 511;
            int n = r >> 3;
            int k = r & 7;
            *reinterpret_cast<float4*>(&ind_lds[a][n][k * 4]) = src[idx];
        }
    }
    __syncthreads();

    // ---- gate for this wave's 4 rows, col = lane (registers, no LDS) ----
    float gr[4];
    {
        float ga[4] = {0.f, 0.f, 0.f, 0.f};
#pragma unroll
        for (int k = 0; k < 8; ++k) {
            float4 v1k = *reinterpret_cast<const float4*>(&ind_lds[1][lane][k * 4]);
#pragma unroll
            for (int r = 0; r < 4; ++r) {
                float4 a4 = *reinterpret_cast<const float4*>(
                    &ind_lds[0][i_base + wave * 4 + r][k * 4]);  // broadcast
                ga[r] += a4.x * v1k.x + a4.y * v1k.y + a4.z * v1k.z + a4.w * v1k.w;
            }
        }
#pragma unroll
        for (int r = 0; r < 4; ++r) gr[r] = (ga[r] > 0.f) ? 1.f : 0.f;
    }

    // ---- s[a][n] = feature[b,n,:] . ind[a,n,:]  (threads < 192) ----
    if (t < 3 * N) {
        int a = t >> 6, n = t & 63;
        const float4* frow = reinterpret_cast<const float4*>(feature + ((size_t)b * N + n) * D);
        float sa = 0.f;
#pragma unroll
        for (int k = 0; k < 8; ++k) {
            float4 f4 = frow[k];
            float4 i4 = *reinterpret_cast<const float4*>(&ind_lds[a][n][k * 4]);
            sa += f4.x * i4.x + f4.y * i4.y + f4.z * i4.z + f4.w * i4.w;
        }
        s_lds[a][n] = sa;
    }
    __syncthreads();

    // ---- per-lane: u = ind0[lane,:] in 32 VGPRs; s1 pre-scaled ----
    float4 u[8];
#pragma unroll
    for (int k = 0; k < 8; ++k)
        u[k] = *reinterpret_cast<const float4*>(&ind_lds[0][lane][k * 4]);
    const float s1L = s_lds[1][lane] * LOG2E;

    // ---- score: wave rows ig = i_base + wave*4 + r ----
    float score[4];
#pragma unroll
    for (int r = 0; r < 4; ++r) {
        const int   ig  = i_base + wave * 4 + r;
        const float s0L = s_lds[0][ig] * LOG2E;
        float sc = 0.f;
#pragma unroll
        for (int k = 0; k < 8; ++k) {
            float4 v4 = *reinterpret_cast<const float4*>(&ind_lds[1][ig][k * 4]);  // broadcast
#pragma unroll
            for (int c = 0; c < 4; ++c) {
                float aL = s0L * (&u[k].x)[c];
                float bL = s1L * (&v4.x)[c];
                float E  = fexp2(fminf(aL, 0.f) + fminf(bL, 0.f));
                float A  = fmaf(fmaxf(aL, 0.f), LN2, 1.0f);
                float B  = fmaf(fmaxf(bL, 0.f), LN2, 1.0f);
                sc = fmaf(E * A, B, sc);
            }
        }
        score[r] = sc;
    }

    // ---- 4-way-ILP wave softmax over j (64 lanes) ----
    float mx[4], e[4], sm[4];
#pragma unroll
    for (int r = 0; r < 4; ++r) mx[r] = score[r];
#pragma unroll
    for (int off = 32; off >= 1; off >>= 1) {
#pragma unroll
        for (int r = 0; r < 4; ++r) mx[r] = fmaxf(mx[r], __shfl_xor(mx[r], off));
    }
#pragma unroll
    for (int r = 0; r < 4; ++r) e[r] = fexp2((score[r] - mx[r]) * LOG2E);
#pragma unroll
    for (int r = 0; r < 4; ++r) sm[r] = e[r];
#pragma unroll
    for (int off = 32; off >= 1; off >>= 1) {
#pragma unroll
        for (int r = 0; r < 4; ++r) sm[r] += __shfl_xor(sm[r], off);
    }
#pragma unroll
    for (int r = 0; r < 4; ++r) {
        const int ig    = i_base + wave * 4 + r;
        const int i_loc = wave * 4 + r;
        sh_lds[i_loc][lane] = (e[r] * gr[r]) * (s_lds[2][ig] * frcp(sm[r]));
    }
    __syncthreads();

    // ---- phase 2: out[i,:] = sh[i,:] @ ind2; thread = (i_loc, d-quad, j-half) ----
    {
        const int i_loc = t >> 4;
        const int sub   = t & 15;
        const int dq    = sub & 7;
        const int jh    = sub >> 3;
        float4 acc = {0.f, 0.f, 0.f, 0.f};
#pragma unroll
        for (int jj = 0; jj < 32; jj += 4) {
            int j = jh * 32 + jj;
            float4 sh4 = *reinterpret_cast<const float4*>(&sh_lds[i_loc][j]);
#pragma unroll
            for (int c = 0; c < 4; ++c) {
                float4 v4 = *reinterpret_cast<const float4*>(&ind_lds[2][j + c][dq * 4]);
                float  w  = (&sh4.x)[c];
                acc.x = fmaf(w, v4.x, acc.x);
                acc.y = fmaf(w, v4.y, acc.y);
                acc.z = fmaf(w, v4.z, acc.z);
                acc.w = fmaf(w, v4.w, acc.w);
            }
        }
        acc.x += __shfl_xor(acc.x, 8);   // combine j-halves (lanes t, t^8)
        acc.y += __shfl_xor(acc.y, 8);
        acc.z += __shfl_xor(acc.z, 8);
        acc.w += __shfl_xor(acc.w, 8);
        if (jh == 0) {
            *reinterpret_cast<float4*>(out + ((size_t)b * N + i_base + i_loc) * D + dq * 4) = acc;
        }
    }
}
}  // namespace

extern "C" void kernel_launch(void* const* d_in, const int* in_sizes, int n_in,
                              void* d_out, int out_size, void* d_ws, size_t ws_size,
                              hipStream_t stream) {
    const float* feature = (const float*)d_in[0];
    const float* ind     = (const float*)d_in[1];
    float*       out     = (float*)d_out;
    fused<<<1024, 512, 0, stream>>>(feature, ind, out);
}

// Round 5
// 164.845 us; speedup vs baseline: 1.0097x; 1.0097x over previous
//
#include <hip/hip_runtime.h>

namespace {
constexpr int N   = 64;
constexpr int D   = 32;
constexpr int PD  = 36;  // padded ind row (dwords): stride-36 measured conflict-free (r1/r2)
constexpr int SHP = 68;  // sh row pad: measured conflict-free in r2
constexpr float LOG2E = 1.4426950408889634f;
constexpr float LN2   = 0.6931471805599453f;

#if __has_builtin(__builtin_amdgcn_exp2f)
__device__ __forceinline__ float fexp2(float x) { return __builtin_amdgcn_exp2f(x); }
#else
__device__ __forceinline__ float fexp2(float x) { return exp2f(x); }
#endif
#if __has_builtin(__builtin_amdgcn_rcpf)
__device__ __forceinline__ float frcp(float x) { return __builtin_amdgcn_rcpf(x); }
#else
__device__ __forceinline__ float frcp(float x) { return 1.0f / x; }
#endif

// Grid 1024 = 2 blocks per b (32 i-rows each), block 512 (8 waves).
// LDS 37.1 KB -> 4 blocks/CU; launch_bounds(512,6) caps VGPR at 85 (natural
// footprint is ~52 per r3), so occupancy = 4 blocks/CU = 32 waves/CU.
// r4 LESSON: (512,8) forced <=64 VGPR -> compiler spilled to scratch
// (FETCH 127MB, WRITE 259MB, VALUBusy 24%). Cap 6, not 8.
// Single-exp identity (exact):
//   elup1(a)*elup1(b) = exp2(min(aL,0)+min(bL,0)) * (1+max(aL,0)*ln2) * (1+max(bL,0)*ln2)
// with aL,bL pre-scaled by log2e.
__global__ __launch_bounds__(512, 6) void fused(
        const float* __restrict__ feature,
        const float* __restrict__ ind,
        float* __restrict__ out) {
    __shared__ float ind_lds[3][N][PD];   // 27648 B
    __shared__ float s_lds[3][N];         //   768 B
    __shared__ float sh_lds[32][SHP];     //  8704 B   total 37120 B

    const int t      = threadIdx.x;
    const int lane   = t & 63;
    const int wave   = t >> 6;
    const int blk    = blockIdx.x;
    const int b      = blk >> 1;
    const int i_base = (blk & 1) << 5;

    // ---- stage indicator: 1536 float4, 3 per thread, coalesced ----
    {
        const float4* src = reinterpret_cast<const float4*>(ind);
#pragma unroll
        for (int idx = t; idx < 3 * N * D / 4; idx += 512) {
            int a = idx >> 9;
            int r = idx & 511;
            int n = r >> 3;
            int k = r & 7;
            *reinterpret_cast<float4*>(&ind_lds[a][n][k * 4]) = src[idx];
        }
    }
    __syncthreads();

    // ---- gate for this wave's 4 rows, col = lane (registers, no LDS) ----
    float gr[4];
    {
        float ga[4] = {0.f, 0.f, 0.f, 0.f};
#pragma unroll
        for (int k = 0; k < 8; ++k) {
            float4 v1k = *reinterpret_cast<const float4*>(&ind_lds[1][lane][k * 4]);
#pragma unroll
            for (int r = 0; r < 4; ++r) {
                float4 a4 = *reinterpret_cast<const float4*>(
                    &ind_lds[0][i_base + wave * 4 + r][k * 4]);  // broadcast
                ga[r] += a4.x * v1k.x + a4.y * v1k.y + a4.z * v1k.z + a4.w * v1k.w;
            }
        }
#pragma unroll
        for (int r = 0; r < 4; ++r) gr[r] = (ga[r] > 0.f) ? 1.f : 0.f;
    }

    // ---- s[a][n] = feature[b,n,:] . ind[a,n,:]  (threads < 192) ----
    if (t < 3 * N) {
        int a = t >> 6, n = t & 63;
        const float4* frow = reinterpret_cast<const float4*>(feature + ((size_t)b * N + n) * D);
        float sa = 0.f;
#pragma unroll
        for (int k = 0; k < 8; ++k) {
            float4 f4 = frow[k];
            float4 i4 = *reinterpret_cast<const float4*>(&ind_lds[a][n][k * 4]);
            sa += f4.x * i4.x + f4.y * i4.y + f4.z * i4.z + f4.w * i4.w;
        }
        s_lds[a][n] = sa;
    }
    __syncthreads();

    // ---- per-lane: u = ind0[lane,:] in 32 VGPRs; s1 pre-scaled ----
    float4 u[8];
#pragma unroll
    for (int k = 0; k < 8; ++k)
        u[k] = *reinterpret_cast<const float4*>(&ind_lds[0][lane][k * 4]);
    const float s1L = s_lds[1][lane] * LOG2E;

    // ---- score: wave rows ig = i_base + wave*4 + r ----
    float score[4];
#pragma unroll
    for (int r = 0; r < 4; ++r) {
        const int   ig  = i_base + wave * 4 + r;
        const float s0L = s_lds[0][ig] * LOG2E;
        float sc = 0.f;
#pragma unroll
        for (int k = 0; k < 8; ++k) {
            float4 v4 = *reinterpret_cast<const float4*>(&ind_lds[1][ig][k * 4]);  // broadcast
#pragma unroll
            for (int c = 0; c < 4; ++c) {
                float aL = s0L * (&u[k].x)[c];
                float bL = s1L * (&v4.x)[c];
                float E  = fexp2(fminf(aL, 0.f) + fminf(bL, 0.f));
                float A  = fmaf(fmaxf(aL, 0.f), LN2, 1.0f);
                float B  = fmaf(fmaxf(bL, 0.f), LN2, 1.0f);
                sc = fmaf(E * A, B, sc);
            }
        }
        score[r] = sc;
    }

    // ---- 4-way-ILP wave softmax over j (64 lanes) ----
    float mx[4], e[4], sm[4];
#pragma unroll
    for (int r = 0; r < 4; ++r) mx[r] = score[r];
#pragma unroll
    for (int off = 32; off >= 1; off >>= 1) {
#pragma unroll
        for (int r = 0; r < 4; ++r) mx[r] = fmaxf(mx[r], __shfl_xor(mx[r], off));
    }
#pragma unroll
    for (int r = 0; r < 4; ++r) e[r] = fexp2((score[r] - mx[r]) * LOG2E);
#pragma unroll
    for (int r = 0; r < 4; ++r) sm[r] = e[r];
#pragma unroll
    for (int off = 32; off >= 1; off >>= 1) {
#pragma unroll
        for (int r = 0; r < 4; ++r) sm[r] += __shfl_xor(sm[r], off);
    }
#pragma unroll
    for (int r = 0; r < 4; ++r) {
        const int ig    = i_base + wave * 4 + r;
        const int i_loc = wave * 4 + r;
        sh_lds[i_loc][lane] = (e[r] * gr[r]) * (s_lds[2][ig] * frcp(sm[r]));
    }
    __syncthreads();

    // ---- phase 2: out[i,:] = sh[i,:] @ ind2; thread = (i_loc, d-quad, j-half) ----
    {
        const int i_loc = t >> 4;
        const int sub   = t & 15;
        const int dq    = sub & 7;
        const int jh    = sub >> 3;
        float4 acc = {0.f, 0.f, 0.f, 0.f};
#pragma unroll
        for (int jj = 0; jj < 32; jj += 4) {
            int j = jh * 32 + jj;
            float4 sh4 = *reinterpret_cast<const float4*>(&sh_lds[i_loc][j]);
#pragma unroll
            for (int c = 0; c < 4; ++c) {
                float4 v4 = *reinterpret_cast<const float4*>(&ind_lds[2][j + c][dq * 4]);
                float  w  = (&sh4.x)[c];
                acc.x = fmaf(w, v4.x, acc.x);
                acc.y = fmaf(w, v4.y, acc.y);
                acc.z = fmaf(w, v4.z, acc.z);
                acc.w = fmaf(w, v4.w, acc.w);
            }
        }
        acc.x += __shfl_xor(acc.x, 8);   // combine j-halves (lanes t, t^8)
        acc.y += __shfl_xor(acc.y, 8);
        acc.z += __shfl_xor(acc.z, 8);
        acc.w += __shfl_xor(acc.w, 8);
        if (jh == 0) {
            *reinterpret_cast<float4*>(out + ((size_t)b * N + i_base + i_loc) * D + dq * 4) = acc;
        }
    }
}
}  // namespace

extern "C" void kernel_launch(void* const* d_in, const int* in_sizes, int n_in,
                              void* d_out, int out_size, void* d_ws, size_t ws_size,
                              hipStream_t stream) {
    const float* feature = (const float*)d_in[0];
    const float* ind     = (const float*)d_in[1];
    float*       out     = (float*)d_out;
    fused<<<1024, 512, 0, stream>>>(feature, ind, out);
}

// Round 6
// 118.901 us; speedup vs baseline: 1.3999x; 1.3864x over previous
//
#include <hip/hip_runtime.h>

namespace {
constexpr int N   = 64;
constexpr int D   = 32;
constexpr int PD  = 36;  // padded ind row (dwords): stride-36 measured conflict-free (r1/r2)
constexpr int SHP = 68;  // sh row pad: measured conflict-free in r2
constexpr float LOG2E = 1.4426950408889634f;
constexpr float LN2   = 0.6931471805599453f;

#if __has_builtin(__builtin_amdgcn_exp2f)
__device__ __forceinline__ float fexp2(float x) { return __builtin_amdgcn_exp2f(x); }
#else
__device__ __forceinline__ float fexp2(float x) { return exp2f(x); }
#endif
#if __has_builtin(__builtin_amdgcn_rcpf)
__device__ __forceinline__ float frcp(float x) { return __builtin_amdgcn_rcpf(x); }
#else
__device__ __forceinline__ float frcp(float x) { return 1.0f / x; }
#endif

// Grid 1024 = 2 blocks per b (32 i-rows each), block 512 (8 waves).
// LDS 37.1 KB -> 4 blocks/CU possible. __launch_bounds__(512,4): VERIFIED
// no-spill config (r3: 52 VGPR, FETCH 2.3MB). r4 (512,8) and r5 (512,6)
// LESSON: both push the allocator into scratch-spill (VGPR 32/40, 400+MB
// of HBM spill traffic, VALUBusy ~21%). (512,4) is a minimum, not a cap:
// if natural allocation lands <=64 VGPR the HW can still run 8 waves/SIMD.
// Single-exp identity (exact):
//   elup1(a)*elup1(b) = exp2(min(aL,0)+min(bL,0)) * (1+max(aL,0)*ln2) * (1+max(bL,0)*ln2)
// with aL,bL pre-scaled by log2e.
__global__ __launch_bounds__(512, 4) void fused(
        const float* __restrict__ feature,
        const float* __restrict__ ind,
        float* __restrict__ out) {
    __shared__ float ind_lds[3][N][PD];   // 27648 B
    __shared__ float s_lds[3][N];         //   768 B
    __shared__ float sh_lds[32][SHP];     //  8704 B   total 37120 B

    const int t      = threadIdx.x;
    const int lane   = t & 63;
    const int wave   = t >> 6;
    const int blk    = blockIdx.x;
    const int b      = blk >> 1;
    const int i_base = (blk & 1) << 5;

    // ---- stage indicator: 1536 float4, 3 per thread, coalesced ----
    {
        const float4* src = reinterpret_cast<const float4*>(ind);
#pragma unroll
        for (int idx = t; idx < 3 * N * D / 4; idx += 512) {
            int a = idx >> 9;
            int r = idx & 511;
            int n = r >> 3;
            int k = r & 7;
            *reinterpret_cast<float4*>(&ind_lds[a][n][k * 4]) = src[idx];
        }
    }
    __syncthreads();

    // ---- gate for this wave's 4 rows, col = lane (registers, no LDS) ----
    float gr[4];
    {
        float ga[4] = {0.f, 0.f, 0.f, 0.f};
#pragma unroll
        for (int k = 0; k < 8; ++k) {
            float4 v1k = *reinterpret_cast<const float4*>(&ind_lds[1][lane][k * 4]);
#pragma unroll
            for (int r = 0; r < 4; ++r) {
                float4 a4 = *reinterpret_cast<const float4*>(
                    &ind_lds[0][i_base + wave * 4 + r][k * 4]);  // broadcast
                ga[r] += a4.x * v1k.x + a4.y * v1k.y + a4.z * v1k.z + a4.w * v1k.w;
            }
        }
#pragma unroll
        for (int r = 0; r < 4; ++r) gr[r] = (ga[r] > 0.f) ? 1.f : 0.f;
    }

    // ---- s[a][n] = feature[b,n,:] . ind[a,n,:]  (threads < 192) ----
    if (t < 3 * N) {
        int a = t >> 6, n = t & 63;
        const float4* frow = reinterpret_cast<const float4*>(feature + ((size_t)b * N + n) * D);
        float sa = 0.f;
#pragma unroll
        for (int k = 0; k < 8; ++k) {
            float4 f4 = frow[k];
            float4 i4 = *reinterpret_cast<const float4*>(&ind_lds[a][n][k * 4]);
            sa += f4.x * i4.x + f4.y * i4.y + f4.z * i4.z + f4.w * i4.w;
        }
        s_lds[a][n] = sa;
    }
    __syncthreads();

    // ---- per-lane: u = ind0[lane,:] in 32 VGPRs; s1 pre-scaled ----
    float4 u[8];
#pragma unroll
    for (int k = 0; k < 8; ++k)
        u[k] = *reinterpret_cast<const float4*>(&ind_lds[0][lane][k * 4]);
    const float s1L = s_lds[1][lane] * LOG2E;

    // ---- score: wave rows ig = i_base + wave*4 + r ----
    float score[4];
#pragma unroll
    for (int r = 0; r < 4; ++r) {
        const int   ig  = i_base + wave * 4 + r;
        const float s0L = s_lds[0][ig] * LOG2E;
        float sc = 0.f;
#pragma unroll
        for (int k = 0; k < 8; ++k) {
            float4 v4 = *reinterpret_cast<const float4*>(&ind_lds[1][ig][k * 4]);  // broadcast
#pragma unroll
            for (int c = 0; c < 4; ++c) {
                float aL = s0L * (&u[k].x)[c];
                float bL = s1L * (&v4.x)[c];
                float E  = fexp2(fminf(aL, 0.f) + fminf(bL, 0.f));
                float A  = fmaf(fmaxf(aL, 0.f), LN2, 1.0f);
                float B  = fmaf(fmaxf(bL, 0.f), LN2, 1.0f);
                sc = fmaf(E * A, B, sc);
            }
        }
        score[r] = sc;
    }

    // ---- 4-way-ILP wave softmax over j (64 lanes) ----
    float mx[4], e[4], sm[4];
#pragma unroll
    for (int r = 0; r < 4; ++r) mx[r] = score[r];
#pragma unroll
    for (int off = 32; off >= 1; off >>= 1) {
#pragma unroll
        for (int r = 0; r < 4; ++r) mx[r] = fmaxf(mx[r], __shfl_xor(mx[r], off));
    }
#pragma unroll
    for (int r = 0; r < 4; ++r) e[r] = fexp2((score[r] - mx[r]) * LOG2E);
#pragma unroll
    for (int r = 0; r < 4; ++r) sm[r] = e[r];
#pragma unroll
    for (int off = 32; off >= 1; off >>= 1) {
#pragma unroll
        for (int r = 0; r < 4; ++r) sm[r] += __shfl_xor(sm[r], off);
    }
#pragma unroll
    for (int r = 0; r < 4; ++r) {
        const int ig    = i_base + wave * 4 + r;
        const int i_loc = wave * 4 + r;
        sh_lds[i_loc][lane] = (e[r] * gr[r]) * (s_lds[2][ig] * frcp(sm[r]));
    }
    __syncthreads();

    // ---- phase 2: out[i,:] = sh[i,:] @ ind2; thread = (i_loc, d-quad, j-half) ----
    {
        const int i_loc = t >> 4;
        const int sub   = t & 15;
        const int dq    = sub & 7;
        const int jh    = sub >> 3;
        float4 acc = {0.f, 0.f, 0.f, 0.f};
#pragma unroll
        for (int jj = 0; jj < 32; jj += 4) {
            int j = jh * 32 + jj;
            float4 sh4 = *reinterpret_cast<const float4*>(&sh_lds[i_loc][j]);
#pragma unroll
            for (int c = 0; c < 4; ++c) {
                float4 v4 = *reinterpret_cast<const float4*>(&ind_lds[2][j + c][dq * 4]);
                float  w  = (&sh4.x)[c];
                acc.x = fmaf(w, v4.x, acc.x);
                acc.y = fmaf(w, v4.y, acc.y);
                acc.z = fmaf(w, v4.z, acc.z);
                acc.w = fmaf(w, v4.w, acc.w);
            }
        }
        acc.x += __shfl_xor(acc.x, 8);   // combine j-halves (lanes t, t^8)
        acc.y += __shfl_xor(acc.y, 8);
        acc.z += __shfl_xor(acc.z, 8);
        acc.w += __shfl_xor(acc.w, 8);
        if (jh == 0) {
            *reinterpret_cast<float4*>(out + ((size_t)b * N + i_base + i_loc) * D + dq * 4) = acc;
        }
    }
}
}  // namespace

extern "C" void kernel_launch(void* const* d_in, const int* in_sizes, int n_in,
                              void* d_out, int out_size, void* d_ws, size_t ws_size,
                              hipStream_t stream) {
    const float* feature = (const float*)d_in[0];
    const float* ind     = (const float*)d_in[1];
    float*       out     = (float*)d_out;
    fused<<<1024, 512, 0, stream>>>(feature, ind, out);
}

// Round 7
// 88.041 us; speedup vs baseline: 1.8905x; 1.3505x over previous
//
#include <hip/hip_runtime.h>

namespace {
constexpr int N   = 64;
constexpr int D   = 32;
constexpr int PD  = 36;   // padded ind row (dwords): stride-36 measured conflict-free (r1/r2)
constexpr int SHP = 196;  // sh row pad: 196 % 32 == 68 % 32 == 4 -> identical banks to the
                          // measured-free 68; sized UP to push LDS to 53760 B so the
                          // compiler's LDS-implied occupancy target is 3 blocks/CU
                          // (6 waves/EU -> VGPR cap 85), not 4 (cap 64 -> spills, r4-r6).
constexpr float LOG2E = 1.4426950408889634f;
constexpr float LN2   = 0.6931471805599453f;

#if __has_builtin(__builtin_amdgcn_exp2f)
__device__ __forceinline__ float fexp2(float x) { return __builtin_amdgcn_exp2f(x); }
#else
__device__ __forceinline__ float fexp2(float x) { return exp2f(x); }
#endif
#if __has_builtin(__builtin_amdgcn_rcpf)
__device__ __forceinline__ float frcp(float x) { return __builtin_amdgcn_rcpf(x); }
#else
__device__ __forceinline__ float frcp(float x) { return 1.0f / x; }
#endif

// Grid 1024 = 2 blocks per b (32 i-rows each), block 512 (8 waves).
// COMPILER MODEL (r3 vs r4/r5/r6 evidence): the VGPR allocator targets the
// LDS-implied max occupancy and spills scratch to reach it. LDS 37.4 KB ->
// target 64 VGPR -> 100+ MB spill traffic (r4/r5/r6). LDS 62.4 KB -> target
// 128 -> clean 52 (r3). Here: LDS 53.8 KB -> 3 blocks/CU, target 85 VGPR,
// natural pressure ~70 -> clean, 24 waves/CU.
// Gate: wave-uniform __ballot bitmasks (SGPR pairs) -> zero VGPR/LDS cost
// across the score loop; applied as (mask>>lane)&1.
// Single-exp identity (exact):
//   elup1(a)*elup1(b) = exp2(min(aL,0)+min(bL,0)) * (1+max(aL,0)*ln2) * (1+max(bL,0)*ln2)
__global__ __launch_bounds__(512, 4) void fused(
        const float* __restrict__ feature,
        const float* __restrict__ ind,
        float* __restrict__ out) {
    __shared__ float ind_lds[3][N][PD];   // 27648 B
    __shared__ float s_lds[3][N];         //   768 B
    __shared__ float sh_lds[32][SHP];     // 25088 B   total 53504 B -> 3 blocks/CU

    const int t      = threadIdx.x;
    const int lane   = t & 63;
    const int wave   = t >> 6;
    const int blk    = blockIdx.x;
    const int b      = blk >> 1;
    const int i_base = (blk & 1) << 5;

    // ---- stage indicator: 1536 float4, 3 per thread, coalesced ----
    {
        const float4* src = reinterpret_cast<const float4*>(ind);
#pragma unroll
        for (int idx = t; idx < 3 * N * D / 4; idx += 512) {
            int a = idx >> 9;
            int r = idx & 511;
            int n = r >> 3;
            int k = r & 7;
            *reinterpret_cast<float4*>(&ind_lds[a][n][k * 4]) = src[idx];
        }
    }
    __syncthreads();

    // ---- gate bitmasks for this wave's 4 rows (SGPR-resident, ~0 pressure) ----
    // gate[ig][lane] = 1[ ind0[ig,:] . ind1[lane,:] > 0 ]
    unsigned long long gmask[4];
    {
        float ga[4] = {0.f, 0.f, 0.f, 0.f};
#pragma unroll
        for (int k = 0; k < 8; ++k) {
            float4 w4 = *reinterpret_cast<const float4*>(&ind_lds[1][lane][k * 4]);  // lane read
#pragma unroll
            for (int r = 0; r < 4; ++r) {
                float4 a4 = *reinterpret_cast<const float4*>(
                    &ind_lds[0][i_base + wave * 4 + r][k * 4]);                      // broadcast
                ga[r] += a4.x * w4.x + a4.y * w4.y + a4.z * w4.z + a4.w * w4.w;
            }
        }
#pragma unroll
        for (int r = 0; r < 4; ++r) gmask[r] = __ballot(ga[r] > 0.f);
    }

    // ---- s[a][n] = feature[b,n,:] . ind[a,n,:]  (threads < 192) ----
    if (t < 3 * N) {
        int a = t >> 6, n = t & 63;
        const float4* frow = reinterpret_cast<const float4*>(feature + ((size_t)b * N + n) * D);
        float sa = 0.f;
#pragma unroll
        for (int k = 0; k < 8; ++k) {
            float4 f4 = frow[k];
            float4 i4 = *reinterpret_cast<const float4*>(&ind_lds[a][n][k * 4]);
            sa += f4.x * i4.x + f4.y * i4.y + f4.z * i4.z + f4.w * i4.w;
        }
        s_lds[a][n] = sa;
    }
    __syncthreads();

    // ---- per-lane: u = ind0[lane,:] in 32 VGPRs; s1 pre-scaled ----
    float4 u[8];
#pragma unroll
    for (int k = 0; k < 8; ++k)
        u[k] = *reinterpret_cast<const float4*>(&ind_lds[0][lane][k * 4]);
    const float s1L = s_lds[1][lane] * LOG2E;

    // ---- score: wave rows ig = i_base + wave*4 + r ----
    float score[4];
#pragma unroll
    for (int r = 0; r < 4; ++r) {
        const int   ig  = i_base + wave * 4 + r;
        const float s0L = s_lds[0][ig] * LOG2E;
        float sc = 0.f;
#pragma unroll
        for (int k = 0; k < 8; ++k) {
            float4 v4 = *reinterpret_cast<const float4*>(&ind_lds[1][ig][k * 4]);  // broadcast
#pragma unroll
            for (int c = 0; c < 4; ++c) {
                float aL = s0L * (&u[k].x)[c];
                float bL = s1L * (&v4.x)[c];
                float E  = fexp2(fminf(aL, 0.f) + fminf(bL, 0.f));
                float A  = fmaf(fmaxf(aL, 0.f), LN2, 1.0f);
                float B  = fmaf(fmaxf(bL, 0.f), LN2, 1.0f);
                sc = fmaf(E * A, B, sc);
            }
        }
        score[r] = sc;
    }

    // ---- 4-way-ILP wave softmax over j (64 lanes) ----
    float mx[4], e[4], sm[4];
#pragma unroll
    for (int r = 0; r < 4; ++r) mx[r] = score[r];
#pragma unroll
    for (int off = 32; off >= 1; off >>= 1) {
#pragma unroll
        for (int r = 0; r < 4; ++r) mx[r] = fmaxf(mx[r], __shfl_xor(mx[r], off));
    }
#pragma unroll
    for (int r = 0; r < 4; ++r) e[r] = fexp2((score[r] - mx[r]) * LOG2E);
#pragma unroll
    for (int r = 0; r < 4; ++r) sm[r] = e[r];
#pragma unroll
    for (int off = 32; off >= 1; off >>= 1) {
#pragma unroll
        for (int r = 0; r < 4; ++r) sm[r] += __shfl_xor(sm[r], off);
    }
#pragma unroll
    for (int r = 0; r < 4; ++r) {
        const int ig    = i_base + wave * 4 + r;
        const int i_loc = wave * 4 + r;
        const float g   = (float)((gmask[r] >> lane) & 1ull);
        sh_lds[i_loc][lane] = (e[r] * g) * (s_lds[2][ig] * frcp(sm[r]));
    }
    __syncthreads();

    // ---- phase 2: out[i,:] = sh[i,:] @ ind2; thread = (i_loc, d-quad, j-half) ----
    {
        const int i_loc = t >> 4;
        const int sub   = t & 15;
        const int dq    = sub & 7;
        const int jh    = sub >> 3;
        float4 acc = {0.f, 0.f, 0.f, 0.f};
#pragma unroll
        for (int jj = 0; jj < 32; jj += 4) {
            int j = jh * 32 + jj;
            float4 sh4 = *reinterpret_cast<const float4*>(&sh_lds[i_loc][j]);
#pragma unroll
            for (int c = 0; c < 4; ++c) {
                float4 v4 = *reinterpret_cast<const float4*>(&ind_lds[2][j + c][dq * 4]);
                float  w  = (&sh4.x)[c];
                acc.x = fmaf(w, v4.x, acc.x);
                acc.y = fmaf(w, v4.y, acc.y);
                acc.z = fmaf(w, v4.z, acc.z);
                acc.w = fmaf(w, v4.w, acc.w);
            }
        }
        acc.x += __shfl_xor(acc.x, 8);   // combine j-halves (lanes t, t^8)
        acc.y += __shfl_xor(acc.y, 8);
        acc.z += __shfl_xor(acc.z, 8);
        acc.w += __shfl_xor(acc.w, 8);
        if (jh == 0) {
            *reinterpret_cast<float4*>(out + ((size_t)b * N + i_base + i_loc) * D + dq * 4) = acc;
        }
    }
}
}  // namespace

extern "C" void kernel_launch(void* const* d_in, const int* in_sizes, int n_in,
                              void* d_out, int out_size, void* d_ws, size_t ws_size,
                              hipStream_t stream) {
    const float* feature = (const float*)d_in[0];
    const float* ind     = (const float*)d_in[1];
    float*       out     = (float*)d_out;
    fused<<<1024, 512, 0, stream>>>(feature, ind, out);
}